// Round 8
// baseline (258.282 us; speedup 1.0000x reference)
//
#include <hip/hip_runtime.h>
#include <hip/hip_bf16.h>

#define NEMB  4096
#define DIM   128
#define NROWS 32768
#define MARGIN 3.5e-4f   // >= 2x(approx err ~3.5e-5); validated r5-r7
#define RPB   64         // rows per block -> grid 512

typedef _Float16 half8  __attribute__((ext_vector_type(8)));
typedef _Float16 half4v __attribute__((ext_vector_type(4)));
typedef _Float16 half2v __attribute__((ext_vector_type(2)));
typedef float    float4v __attribute__((ext_vector_type(4)));

__device__ __forceinline__ half2v hmin2(half2v a, half2v b) {
    half2v r;
    r.x = (a.x < b.x) ? a.x : b.x;
    r.y = (a.y < b.y) ? a.y : b.y;
    return r;
}

// ---------------- K1: W only — split to fp16 (scale 2^16) + numpy-pairwise ||w||^2 ----
__launch_bounds__(256)
__global__ void k_prep(const float* __restrict__ W, _Float16* __restrict__ Wh,
                       float* __restrict__ sww) {
    const int b = blockIdx.x;               // 512 blocks, 8 rows each
    const int t = threadIdx.x;
    const int rbase = b * 8;

    const size_t i4 = (size_t)rbase * 32 + t;
    const float4 v = ((const float4*)W)[i4];
    half4v hv = { (_Float16)(v.x * 65536.0f), (_Float16)(v.y * 65536.0f),
                  (_Float16)(v.z * 65536.0f), (_Float16)(v.w * 65536.0f) };
    *(half4v*)(Wh + i4 * 4) = hv;

    if (t < 64) {
        const int row = rbase + (t >> 3);
        const int j   = t & 7;
        const float* p = W + (size_t)row * DIM + j;
        float vv = p[0];
        float r = __fmul_rn(vv, vv);
        #pragma unroll
        for (int q = 1; q < 16; ++q) { vv = p[q * 8]; r = __fadd_rn(r, __fmul_rn(vv, vv)); }
        float o = __shfl_xor(r, 1, 64); r = __fadd_rn(r, o);
        o = __shfl_xor(r, 2, 64); r = __fadd_rn(r, o);
        o = __shfl_xor(r, 4, 64); r = __fadd_rn(r, o);
        if (j == 0) sww[row] = r;
    }
}

// ---------------- K2: mega kernel, barrier-free K-loop ----------------
// Per block: 64 x-rows. X fragments converted f32->fp16 into registers (whole kernel).
// W fragments stream global->VGPR per wave (no LDS staging, no syncthreads in loop).
// D = W'*X^T (m=codes, n=xrows): C/D n(col)=lane&15, m(row)=quad*4+reg.
// Per-16-code group-min: 3 in-reg mins + 2 shuffles -> swizzled LDS gbuf.
// One barrier, then fused flag + exact numpy-fp32 refine + outputs + loss partial.
__launch_bounds__(256, 3)
__global__ void k_main(const float* __restrict__ x, const _Float16* __restrict__ Wh,
                       const float* __restrict__ W, const float* __restrict__ sww,
                       float* __restrict__ out0, float* __restrict__ out1,
                       float* __restrict__ out_idx, float* __restrict__ part) {
    __shared__ _Float16 gbuf[RPB * 256];    // 32 KB, slot-swizzled: (row,g) at slot (g+2row)&255
    __shared__ float sxx_s[RPB];

    const int tid  = threadIdx.x;
    const int wv   = tid >> 6;
    const int lane = tid & 63;
    const int l15  = lane & 15;
    const int quad = lane >> 4;
    const int r0   = blockIdx.x * RPB;

    // --- setup: X fragments f32 -> fp16 registers (scale 1; |x|<6 fits fp16) ---
    half8 bfr[4][4];
    #pragma unroll
    for (int tn = 0; tn < 4; ++tn) {
        const float* xr = x + (size_t)(r0 + tn * 16 + l15) * DIM + quad * 8;
        #pragma unroll
        for (int c = 0; c < 4; ++c) {
            const float4 u0 = *(const float4*)(xr + c * 32);
            const float4 u1 = *(const float4*)(xr + c * 32 + 4);
            bfr[tn][c] = (half8){ (_Float16)u0.x, (_Float16)u0.y, (_Float16)u0.z, (_Float16)u0.w,
                                  (_Float16)u1.x, (_Float16)u1.y, (_Float16)u1.z, (_Float16)u1.w };
        }
    }

    // --- setup: sxx for the 64 rows, exact numpy-pairwise order (L1-hot re-read) ---
    #pragma unroll
    for (int p = 0; p < 2; ++p) {
        const int rl = p * 32 + wv * 8 + (lane >> 3);
        const int j  = lane & 7;
        const float* ps = x + (size_t)(r0 + rl) * DIM + j;
        float vv = ps[0];
        float r = __fmul_rn(vv, vv);
        #pragma unroll
        for (int q = 1; q < 16; ++q) { vv = ps[q * 8]; r = __fadd_rn(r, __fmul_rn(vv, vv)); }
        float o = __shfl_xor(r, 1, 64); r = __fadd_rn(r, o);
        o = __shfl_xor(r, 2, 64); r = __fadd_rn(r, o);
        o = __shfl_xor(r, 4, 64); r = __fadd_rn(r, o);
        if (j == 0) sxx_s[rl] = r;
    }

    // --- main loop over 32 code-blocks: no barriers ---
    const _Float16* Ab = Wh + (size_t)(wv * 32 + l15) * DIM + quad * 8;
    for (int cb = 0; cb < 32; ++cb) {
        const _Float16* Ap = Ab + (size_t)cb * 128 * DIM;
        half8 a0[4], a1[4];
        #pragma unroll
        for (int c = 0; c < 4; ++c) {
            a0[c] = *(const half8*)(Ap + c * 32);
            a1[c] = *(const half8*)(Ap + 16 * DIM + c * 32);
        }

        float4v acc[2][4];
        #pragma unroll
        for (int tm = 0; tm < 2; ++tm)
            #pragma unroll
            for (int tn = 0; tn < 4; ++tn) acc[tm][tn] = (float4v){0.f, 0.f, 0.f, 0.f};

        #pragma unroll
        for (int c = 0; c < 4; ++c)
            #pragma unroll
            for (int tn = 0; tn < 4; ++tn) {
                acc[0][tn] = __builtin_amdgcn_mfma_f32_16x16x32_f16(a0[c], bfr[tn][c], acc[0][tn], 0, 0, 0);
                acc[1][tn] = __builtin_amdgcn_mfma_f32_16x16x32_f16(a1[c], bfr[tn][c], acc[1][tn], 0, 0, 0);
            }

        // epilogue: s~ = sww - acc*2^-15; 16-code group minima -> gbuf
        const float4 sw0 = ((const float4*)sww)[cb * 32 + wv * 8 + 0 + quad];
        const float4 sw1 = ((const float4*)sww)[cb * 32 + wv * 8 + 4 + quad];
        #pragma unroll
        for (int tn = 0; tn < 4; ++tn) {
            float s0 = fmaf(acc[0][tn][0], -0x1p-15f, sw0.x);
            s0 = fminf(s0, fmaf(acc[0][tn][1], -0x1p-15f, sw0.y));
            s0 = fminf(s0, fmaf(acc[0][tn][2], -0x1p-15f, sw0.z));
            s0 = fminf(s0, fmaf(acc[0][tn][3], -0x1p-15f, sw0.w));
            float s1 = fmaf(acc[1][tn][0], -0x1p-15f, sw1.x);
            s1 = fminf(s1, fmaf(acc[1][tn][1], -0x1p-15f, sw1.y));
            s1 = fminf(s1, fmaf(acc[1][tn][2], -0x1p-15f, sw1.z));
            s1 = fminf(s1, fmaf(acc[1][tn][3], -0x1p-15f, sw1.w));
            union { half2v h; int u; } cur, oth;
            cur.h.x = (_Float16)s0; cur.h.y = (_Float16)s1;   // groups cb*8+wv*2, +1
            oth.u = __shfl_xor(cur.u, 16, 64); cur.h = hmin2(cur.h, oth.h);
            oth.u = __shfl_xor(cur.u, 32, 64); cur.h = hmin2(cur.h, oth.h);
            if (quad == 0) {
                const int row  = tn * 16 + l15;
                const int slot = (cb * 8 + wv * 2 + 2 * row) & 255;
                *(half2v*)((char*)gbuf + row * 512 + slot * 2) = cur.h;
            }
        }
    }

    __syncthreads();   // gbuf + sxx_s complete

    // --- flag + exact refine (numpy fp32 semantics) + outputs (validated r7) ---
    const int chunk = lane & 31;   // groups 8*chunk .. 8*chunk+7 (lanes 32-63 mirror)
    const int cig   = lane >> 2;
    const int kp    = lane & 3;
    for (int t = 0; t < 16; ++t) {
        const int lr  = wv * 16 + t;
        const int row = r0 + lr;

        float v[8];
        #pragma unroll
        for (int k = 0; k < 4; ++k) {
            const int slot = (8 * chunk + 2 * k + 2 * lr) & 255;
            const half2v h = *(const half2v*)((const char*)gbuf + lr * 512 + slot * 2);
            v[2 * k]     = (float)h.x;
            v[2 * k + 1] = (float)h.y;
        }
        float m = v[0];
        #pragma unroll
        for (int k = 1; k < 8; ++k) m = fminf(m, v[k]);
        #pragma unroll
        for (int off = 1; off < 32; off <<= 1) m = fminf(m, __shfl_xor(m, off, 64));
        const float thr = m + MARGIN;

        unsigned bal[8];
        #pragma unroll
        for (int j = 0; j < 8; ++j) bal[j] = (unsigned)__ballot(v[j] <= thr);

        const float sxr = sxx_s[lr];
        const float* xr = x + (size_t)row * DIM;
        const float* xp = xr + kp * 32;
        float bv = 3.0e38f;
        int   bi = 0x7fffffff;

        #pragma unroll
        for (int j = 0; j < 8; ++j) {
            unsigned msk = bal[j];
            while (msk) {
                const int l = __builtin_ctz(msk);
                msk &= msk - 1;
                const int g = l * 8 + j;
                const int c = g * 16 + cig;
                const float* wr = W + (size_t)c * DIM + kp * 32;
                float dot = 0.f;
                #pragma unroll
                for (int k = 0; k < 32; ++k) dot = fmaf(xp[k], wr[k], dot);
                float o = __shfl_xor(dot, 1, 64); dot = __fadd_rn(dot, o);
                o = __shfl_xor(dot, 2, 64); dot = __fadd_rn(dot, o);  // (p0+p1)+(p2+p3)
                const float A = __fadd_rn(sxr, sww[c]);
                const float d = __fsub_rn(A, __fmul_rn(2.0f, dot));
                if (d < bv || (d == bv && c < bi)) { bv = d; bi = c; }
            }
        }
        #pragma unroll
        for (int off = 1; off < 64; off <<= 1) {
            const float ov = __shfl_xor(bv, off, 64);
            const int   oi = __shfl_xor(bi, off, 64);
            if (ov < bv || (ov == bv && oi < bi)) { bv = ov; bi = oi; }
        }

        const float2 wv2 = *(const float2*)(W + (size_t)bi * DIM + lane * 2);
        const float2 xv2 = *(const float2*)(xr + lane * 2);
        const float d0 = wv2.x - xv2.x, d1 = wv2.y - xv2.y;
        float p = fmaf(d0, d0, d1 * d1);
        *(float2*)(out0 + (size_t)row * DIM + lane * 2) = wv2;
        *(float2*)(out1 + (size_t)row * DIM + lane * 2) = wv2;
        #pragma unroll
        for (int off = 32; off > 0; off >>= 1) p += __shfl_down(p, off, 64);
        if (lane == 0) {
            part[row] = p;
            out_idx[row] = (float)bi;
        }
    }
}

// ---------------- K3: reduce 32768 partials -> loss ----------------
__global__ void k_lsum(const float* __restrict__ part, float* __restrict__ out_loss) {
    __shared__ float red[1024];
    const int tid = threadIdx.x;
    const float4* p4 = (const float4*)part;   // 8192 float4
    float s = 0.f;
    #pragma unroll
    for (int i = 0; i < 8; ++i) {
        const float4 v = p4[tid + i * 1024];
        s += (v.x + v.y) + (v.z + v.w);
    }
    red[tid] = s;
    __syncthreads();
    #pragma unroll
    for (int w = 512; w > 0; w >>= 1) {
        if (tid < w) red[tid] += red[tid + w];
        __syncthreads();
    }
    if (tid == 0) out_loss[0] = red[0] * 1.25f / (float)(NROWS * DIM);
}

extern "C" void kernel_launch(void* const* d_in, const int* in_sizes, int n_in,
                              void* d_out, int out_size, void* d_ws, size_t ws_size,
                              hipStream_t stream) {
    const float* x = (const float*)d_in[0];   // [32768,128]
    const float* W = (const float*)d_in[1];   // [4096,128]
    float* out = (float*)d_out;

    float* out_q2d  = out;
    float* out_qst  = out + (size_t)NROWS * DIM;
    float* out_loss = out + (size_t)2 * NROWS * DIM;
    float* out_idx  = out + (size_t)2 * NROWS * DIM + 1;

    // ws layout: sww | part | Wh  (~1.2 MB)
    float* ws   = (float*)d_ws;
    float* sww  = ws;                                   // 4096
    float* part = ws + 4096;                            // 32768
    _Float16* Wh = (_Float16*)(ws + 4096 + 32768);      // 4096*128 fp16

    k_prep<<<NEMB / 8, 256, 0, stream>>>(W, Wh, sww);
    k_main<<<NROWS / RPB, 256, 0, stream>>>(x, Wh, W, sww,
                                            out_q2d, out_qst, out_idx, part);
    k_lsum<<<1, 1024, 0, stream>>>(part, out_loss);
}

// Round 9
// 218.931 us; speedup vs baseline: 1.1797x; 1.1797x over previous
//
#include <hip/hip_runtime.h>
#include <hip/hip_bf16.h>

#define NEMB  4096
#define DIM   128
#define NROWS 32768
#define MARGIN 3.5e-4f   // >= 5x approx-error bound; validated r5-r8
#define RPB   128        // rows per block -> grid 256 = 1 block/CU
#define CHUNK 128        // codes per K-loop iteration
#define NITER 32         // NEMB/CHUNK

typedef _Float16 half8  __attribute__((ext_vector_type(8)));
typedef _Float16 half4v __attribute__((ext_vector_type(4)));
typedef _Float16 half2v __attribute__((ext_vector_type(2)));
typedef float    float16v __attribute__((ext_vector_type(16)));

typedef const __attribute__((address_space(1))) void* gas_ptr;
typedef __attribute__((address_space(3))) void*       las_ptr;

__device__ __forceinline__ void gload16(const void* g, void* l) {
    __builtin_amdgcn_global_load_lds((gas_ptr)g, (las_ptr)l, 16, 0, 0);
}

__device__ __forceinline__ half2v hmin2(half2v a, half2v b) {
    half2v r;
    r.x = (a.x < b.x) ? a.x : b.x;
    r.y = (a.y < b.y) ? a.y : b.y;
    return r;
}

// ---------------- K1: W -> fp16 (scale 2^16) in MFMA-fragment-major layout + ||w||^2 ----
// Wh2 layout: per (slab s = code/32, kchunk c = k/16): 1KB block; half index
// (s*8+c)*512 + (h*32 + (code&31))*8 + (k&7), h=(k>>3)&1.  In k_main, lane reads
// byte lane*16 of a block => fully coalesced loads and exact A-fragment order.
__launch_bounds__(256)
__global__ void k_prep(const float* __restrict__ W, _Float16* __restrict__ Wh2,
                       float* __restrict__ sww) {
    const int b = blockIdx.x;               // 512 blocks, 8 rows each
    const int t = threadIdx.x;
    const int rbase = b * 8;

    const int i4 = rbase * 32 + t;
    const float4 v = ((const float4*)W)[i4];
    const int r  = i4 >> 5;
    const int k0 = (i4 & 31) * 4;
    const int s  = r >> 5, cs = r & 31, c = k0 >> 4, h2 = (k0 >> 3) & 1, j0 = k0 & 7;
    half4v hv = { (_Float16)(v.x * 65536.0f), (_Float16)(v.y * 65536.0f),
                  (_Float16)(v.z * 65536.0f), (_Float16)(v.w * 65536.0f) };
    *(half4v*)(Wh2 + (s * 8 + c) * 512 + (h2 * 32 + cs) * 8 + j0) = hv;

    if (t < 64) {   // numpy-pairwise ||w||^2 (exact fp32 semantics, validated r3-r8)
        const int row = rbase + (t >> 3);
        const int j   = t & 7;
        const float* p = W + (size_t)row * DIM + j;
        float vv = p[0];
        float rr = __fmul_rn(vv, vv);
        #pragma unroll
        for (int q = 1; q < 16; ++q) { vv = p[q * 8]; rr = __fadd_rn(rr, __fmul_rn(vv, vv)); }
        float o = __shfl_xor(rr, 1, 64); rr = __fadd_rn(rr, o);
        o = __shfl_xor(rr, 2, 64); rr = __fadd_rn(rr, o);
        o = __shfl_xor(rr, 4, 64); rr = __fadd_rn(rr, o);
        if (j == 0) sww[row] = rr;
    }
}

// ---------------- K2: mega kernel: dbuf-DMA W, 32x32x16 MFMA, LDS gmin, fused refine ----
__global__ __launch_bounds__(512, 2)
void k_main(const float* __restrict__ x, const _Float16* __restrict__ Wh2,
            const float* __restrict__ W, const float* __restrict__ sww,
            float* __restrict__ out0, float* __restrict__ out1,
            float* __restrict__ out_idx, float* __restrict__ part) {
    __shared__ _Float16 sA[2 * CHUNK * DIM];   // 64 KB double buffer
    __shared__ _Float16 gbuf[RPB * 256];       // 64 KB group minima (swizzled)
    __shared__ float ssw[NEMB];                // 16 KB sww copy (keeps epilogue off vmcnt)

    const int tid  = threadIdx.x;
    const int wv   = tid >> 6;      // 0..7
    const int lane = tid & 63;
    const int l31  = lane & 31;
    const int h    = lane >> 5;
    const int r0   = blockIdx.x * RPB;
    const int mt   = wv & 3;        // 32-code slab within chunk
    const int np   = wv >> 2;       // row-half: n-tiles {2np, 2np+1}

    #pragma unroll
    for (int i = 0; i < 2; ++i)
        ((float4*)ssw)[tid + i * 512] = ((const float4*)sww)[tid + i * 512];

    // B fragments: x rows -> fp16 regs (scale 1), B[n=lane&31][k=h*8+j] per 16-k chunk
    half8 bfr[2][8];
    #pragma unroll
    for (int nn = 0; nn < 2; ++nn) {
        const float* xr = x + (size_t)(r0 + (2 * np + nn) * 32 + l31) * DIM + h * 8;
        #pragma unroll
        for (int c = 0; c < 8; ++c) {
            const float4 u0 = *(const float4*)(xr + c * 16);
            const float4 u1 = *(const float4*)(xr + c * 16 + 4);
            bfr[nn][c] = (half8){ (_Float16)u0.x, (_Float16)u0.y, (_Float16)u0.z, (_Float16)u0.w,
                                  (_Float16)u1.x, (_Float16)u1.y, (_Float16)u1.z, (_Float16)u1.w };
        }
    }

    // sxx (numpy-pairwise exact) for rows wv*16..+16, kept in regs (lane j==0 of each octet)
    float sxx_reg[2];
    #pragma unroll
    for (int p = 0; p < 2; ++p) {
        const float* ps = x + (size_t)(r0 + wv * 16 + p * 8 + (lane >> 3)) * DIM + (lane & 7);
        float vv = ps[0];
        float rr = __fmul_rn(vv, vv);
        #pragma unroll
        for (int q = 1; q < 16; ++q) { vv = ps[q * 8]; rr = __fadd_rn(rr, __fmul_rn(vv, vv)); }
        float o = __shfl_xor(rr, 1, 64); rr = __fadd_rn(rr, o);
        o = __shfl_xor(rr, 2, 64); rr = __fadd_rn(rr, o);
        o = __shfl_xor(rr, 4, 64); rr = __fadd_rn(rr, o);
        sxx_reg[p] = rr;
    }

    // prologue DMA: chunk 0 -> buffer 0 (coalesced: Wh2 is fragment-major linear)
    #pragma unroll
    for (int r = 0; r < 4; ++r)
        gload16((const char*)Wh2 + r * 8192 + wv * 1024 + lane * 16,
                (char*)sA + r * 8192 + wv * 1024);

    for (int cb = 0; cb < NITER; ++cb) {
        __syncthreads();   // drains DMA issued one full iteration ago
        if (cb + 1 < NITER) {
            const char* src = (const char*)Wh2 + (size_t)(cb + 1) * (CHUNK * DIM * 2);
            char* dst = (char*)sA + ((cb + 1) & 1) * (CHUNK * DIM * 2);
            #pragma unroll
            for (int r = 0; r < 4; ++r)
                gload16(src + r * 8192 + wv * 1024 + lane * 16, dst + r * 8192 + wv * 1024);
        }

        const _Float16* curb = sA + (cb & 1) * (CHUNK * DIM);
        float16v acc0, acc1;
        #pragma unroll
        for (int i = 0; i < 16; ++i) { acc0[i] = 0.f; acc1[i] = 0.f; }

        #pragma unroll
        for (int c = 0; c < 8; ++c) {
            const half8 a = *(const half8*)(curb + (mt * 8 + c) * 512 + lane * 8);
            acc0 = __builtin_amdgcn_mfma_f32_32x32x16_f16(a, bfr[0][c], acc0, 0, 0, 0);
            acc1 = __builtin_amdgcn_mfma_f32_32x32x16_f16(a, bfr[1][c], acc1, 0, 0, 0);
        }

        // epilogue: s~ = sww - acc*2^-15; two 16-code groups per slab; 1 shfl total
        const int s = cb * 4 + mt;   // global 32-code slab [0,128)
        const float4 swq0 = *(const float4*)((const char*)ssw + s * 128 + h * 16);
        const float4 swq1 = *(const float4*)((const char*)ssw + s * 128 + h * 16 + 32);
        const float4 swq2 = *(const float4*)((const char*)ssw + s * 128 + h * 16 + 64);
        const float4 swq3 = *(const float4*)((const char*)ssw + s * 128 + h * 16 + 96);
        #pragma unroll
        for (int nn = 0; nn < 2; ++nn) {
            const float16v& A = nn ? acc1 : acc0;
            float g0 = fmaf(A[0], -0x1p-15f, swq0.x);
            g0 = fminf(g0, fmaf(A[1], -0x1p-15f, swq0.y));
            g0 = fminf(g0, fmaf(A[2], -0x1p-15f, swq0.z));
            g0 = fminf(g0, fmaf(A[3], -0x1p-15f, swq0.w));
            g0 = fminf(g0, fmaf(A[4], -0x1p-15f, swq1.x));
            g0 = fminf(g0, fmaf(A[5], -0x1p-15f, swq1.y));
            g0 = fminf(g0, fmaf(A[6], -0x1p-15f, swq1.z));
            g0 = fminf(g0, fmaf(A[7], -0x1p-15f, swq1.w));
            float g1 = fmaf(A[8], -0x1p-15f, swq2.x);
            g1 = fminf(g1, fmaf(A[9],  -0x1p-15f, swq2.y));
            g1 = fminf(g1, fmaf(A[10], -0x1p-15f, swq2.z));
            g1 = fminf(g1, fmaf(A[11], -0x1p-15f, swq2.w));
            g1 = fminf(g1, fmaf(A[12], -0x1p-15f, swq3.x));
            g1 = fminf(g1, fmaf(A[13], -0x1p-15f, swq3.y));
            g1 = fminf(g1, fmaf(A[14], -0x1p-15f, swq3.z));
            g1 = fminf(g1, fmaf(A[15], -0x1p-15f, swq3.w));
            union { half2v h2; int u; } cu, ot;
            cu.h2.x = (_Float16)g0; cu.h2.y = (_Float16)g1;   // groups 2s, 2s+1
            ot.u = __shfl_xor(cu.u, 32, 64);
            cu.h2 = hmin2(cu.h2, ot.h2);
            if (h == 0) {
                const int row = (2 * np + nn) * 32 + l31;       // local row
                const int ws  = (s + row) & 127;                // swizzled word slot
                ((int*)gbuf)[row * 128 + ws] = cu.u;
            }
        }
    }

    __syncthreads();

    // ---- fused flag + exact refine (numpy fp32 semantics) + outputs (validated r7/r8) ----
    const int cig = lane >> 2;
    const int kp  = lane & 3;
    for (int t = 0; t < 16; ++t) {
        const int lr  = wv * 16 + t;
        const int row = r0 + lr;

        const int2 gw = *(const int2*)((const char*)gbuf + lr * 512 + lane * 8);
        union { half2v h2; int u; } pa, pb;
        pa.u = gw.x; pb.u = gw.y;
        const float v0 = (float)pa.h2.x, v1 = (float)pa.h2.y;
        const float v2 = (float)pb.h2.x, v3 = (float)pb.h2.y;
        float m = fminf(fminf(v0, v1), fminf(v2, v3));
        #pragma unroll
        for (int off = 1; off < 64; off <<= 1) m = fminf(m, __shfl_xor(m, off, 64));
        const float thr = m + MARGIN;
        unsigned long long bal[4];
        bal[0] = __ballot(v0 <= thr);
        bal[1] = __ballot(v1 <= thr);
        bal[2] = __ballot(v2 <= thr);
        bal[3] = __ballot(v3 <= thr);

        const float sxr = __shfl(sxx_reg[t >> 3], (t & 7) * 8, 64);
        const float* xr = x + (size_t)row * DIM;
        const float* xp = xr + kp * 32;
        float bv = 3.0e38f;
        int   bi = 0x7fffffff;

        #pragma unroll
        for (int j = 0; j < 4; ++j) {
            unsigned long long msk = bal[j];
            while (msk) {
                const int l = __builtin_ctzll(msk);
                msk &= msk - 1;
                const int wsl = 2 * l + (j >> 1);
                const int g   = 2 * ((wsl - lr) & 127) + (j & 1);
                const int c   = g * 16 + cig;
                const float* wr = W + (size_t)c * DIM + kp * 32;
                float dot = 0.f;
                #pragma unroll
                for (int k = 0; k < 32; ++k) dot = fmaf(xp[k], wr[k], dot);
                float o = __shfl_xor(dot, 1, 64); dot = __fadd_rn(dot, o);
                o = __shfl_xor(dot, 2, 64); dot = __fadd_rn(dot, o);
                const float A = __fadd_rn(sxr, ssw[c]);
                const float d = __fsub_rn(A, __fmul_rn(2.0f, dot));
                if (d < bv || (d == bv && c < bi)) { bv = d; bi = c; }
            }
        }
        #pragma unroll
        for (int off = 1; off < 64; off <<= 1) {
            const float ov = __shfl_xor(bv, off, 64);
            const int   oi = __shfl_xor(bi, off, 64);
            if (ov < bv || (ov == bv && oi < bi)) { bv = ov; bi = oi; }
        }

        const float2 wv2 = *(const float2*)(W + (size_t)bi * DIM + lane * 2);
        const float2 xv2 = *(const float2*)(xr + lane * 2);
        const float d0 = wv2.x - xv2.x, d1 = wv2.y - xv2.y;
        float p = fmaf(d0, d0, d1 * d1);
        *(float2*)(out0 + (size_t)row * DIM + lane * 2) = wv2;
        *(float2*)(out1 + (size_t)row * DIM + lane * 2) = wv2;
        #pragma unroll
        for (int off = 32; off > 0; off >>= 1) p += __shfl_down(p, off, 64);
        if (lane == 0) {
            part[row] = p;
            out_idx[row] = (float)bi;
        }
    }
}

// ---------------- K3: reduce 32768 partials -> loss ----------------
__global__ void k_lsum(const float* __restrict__ part, float* __restrict__ out_loss) {
    __shared__ float red[1024];
    const int tid = threadIdx.x;
    const float4* p4 = (const float4*)part;
    float s = 0.f;
    #pragma unroll
    for (int i = 0; i < 8; ++i) {
        const float4 v = p4[tid + i * 1024];
        s += (v.x + v.y) + (v.z + v.w);
    }
    red[tid] = s;
    __syncthreads();
    #pragma unroll
    for (int w = 512; w > 0; w >>= 1) {
        if (tid < w) red[tid] += red[tid + w];
        __syncthreads();
    }
    if (tid == 0) out_loss[0] = red[0] * 1.25f / (float)(NROWS * DIM);
}

extern "C" void kernel_launch(void* const* d_in, const int* in_sizes, int n_in,
                              void* d_out, int out_size, void* d_ws, size_t ws_size,
                              hipStream_t stream) {
    const float* x = (const float*)d_in[0];   // [32768,128]
    const float* W = (const float*)d_in[1];   // [4096,128]
    float* out = (float*)d_out;

    float* out_q2d  = out;
    float* out_qst  = out + (size_t)NROWS * DIM;
    float* out_loss = out + (size_t)2 * NROWS * DIM;
    float* out_idx  = out + (size_t)2 * NROWS * DIM + 1;

    // ws layout: sww | part | Wh2  (~1.2 MB)
    float* ws   = (float*)d_ws;
    float* sww  = ws;                                   // 4096
    float* part = ws + 4096;                            // 32768
    _Float16* Wh2 = (_Float16*)(ws + 4096 + 32768);     // 4096*128 fp16, fragment-major

    k_prep<<<NEMB / 8, 256, 0, stream>>>(W, Wh2, sww);
    k_main<<<NROWS / RPB, 512, 0, stream>>>(x, Wh2, W, sww,
                                            out_q2d, out_qst, out_idx, part);
    k_lsum<<<1, 1024, 0, stream>>>(part, out_loss);
}